// Round 12
// baseline (339.068 us; speedup 1.0000x reference)
//
#include <hip/hip_runtime.h>
#include <hip/hip_bf16.h>
#include <cmath>

// ---------------------------------------------------------------------------
// Problem constants (B=1, T=2048, D=768, H=4, N=25600, KD=128, HQ=512,
// HID_A=44, HID_S=1024, KNN=16)
// ---------------------------------------------------------------------------
#define NEG_INF (-3.402823466e38f)
#define SPLITS 32          // N-splits per head
#define SPN    800         // experts per split
#define GRP    32          // experts per staged LDS group (2 MFMA A-tiles)
#define NGRP   25          // groups per split (800/32)

typedef __attribute__((ext_vector_type(8))) short s16x8;   // 8 bf16 (4 VGPRs)
typedef __attribute__((ext_vector_type(4))) float f32x4;   // MFMA C/D frag

__device__ __forceinline__ unsigned short f2bf(float f) {
    union { float f; unsigned u; } v; v.f = f;
    unsigned u = v.u;
    u += 0x7fffu + ((u >> 16) & 1u);   // round-to-nearest-even
    return (unsigned short)(u >> 16);
}

__device__ __forceinline__ s16x8 pack8(float4 a, float4 b) {
    s16x8 v;
    v[0] = (short)f2bf(a.x); v[1] = (short)f2bf(a.y);
    v[2] = (short)f2bf(a.z); v[3] = (short)f2bf(a.w);
    v[4] = (short)f2bf(b.x); v[5] = (short)f2bf(b.y);
    v[6] = (short)f2bf(b.z); v[7] = (short)f2bf(b.w);
    return v;
}

// ---------------------------------------------------------------------------
// q-projection body reading FP32 x/wq directly (converts during staging, so
// it has NO dependence on the bf16 converter -> can co-run with it).
// q = BN(x @ wq^T + bq) -> bf16 (2048 x 512, K=768). sb in [0,256).
// ---------------------------------------------------------------------------
__device__ __forceinline__ void qproj_body(
        int sb, int tid, const float* __restrict__ A, const float* __restrict__ W,
        unsigned short* __restrict__ outB,
        const float* __restrict__ bq, const float* __restrict__ gamma,
        const float* __restrict__ beta, const float* __restrict__ mean,
        const float* __restrict__ var, char* smem) {
    short (*As)[72] = (short(*)[72])smem;             //  9216 B
    short (*Ws)[72] = (short(*)[72])(smem + 9216);    //  9216 B
    const int m0 = (sb & 31) * 64, n0 = (sb >> 5) * 64;
    const int wv = tid >> 6, lane = tid & 63;
    const int wr = wv >> 1, wc = wv & 1;
    const int lr = lane & 15, lq = lane >> 4;
    f32x4 acc[2][2];
    #pragma unroll
    for (int i = 0; i < 2; ++i)
        #pragma unroll
        for (int j = 0; j < 2; ++j) acc[i][j] = (f32x4){0.f, 0.f, 0.f, 0.f};
    for (int kb = 0; kb < 768; kb += 64) {
        #pragma unroll
        for (int it = 0; it < 2; ++it) {
            int chunk = tid + it * 256;
            int row = chunk >> 3, c8 = (chunk & 7) * 8;
            const float* ap = A + (size_t)(m0 + row) * 768 + kb + c8;
            const float* wp = W + (size_t)(n0 + row) * 768 + kb + c8;
            *(s16x8*)&As[row][c8] = pack8(*(const float4*)ap, *(const float4*)(ap + 4));
            *(s16x8*)&Ws[row][c8] = pack8(*(const float4*)wp, *(const float4*)(wp + 4));
        }
        __syncthreads();
        #pragma unroll
        for (int ks = 0; ks < 2; ++ks) {
            const int k0 = ks * 32 + lq * 8;
            #pragma unroll
            for (int rt = 0; rt < 2; ++rt) {
                s16x8 a = *(const s16x8*)&As[wr * 32 + rt * 16 + lr][k0];
                #pragma unroll
                for (int ct = 0; ct < 2; ++ct) {
                    s16x8 b = *(const s16x8*)&Ws[wc * 32 + ct * 16 + lr][k0];
                    acc[rt][ct] = __builtin_amdgcn_mfma_f32_16x16x32_bf16(a, b, acc[rt][ct], 0, 0, 0);
                }
            }
        }
        __syncthreads();
    }
    // C/D layout: col = lane&15, row = (lane>>4)*4 + r  [verified m89/m91]
    #pragma unroll
    for (int rt = 0; rt < 2; ++rt)
        #pragma unroll
        for (int ct = 0; ct < 2; ++ct)
            #pragma unroll
            for (int r = 0; r < 4; ++r) {
                int m = m0 + wr * 32 + rt * 16 + lq * 4 + r;
                int n = n0 + wc * 32 + ct * 16 + lr;
                float q = acc[rt][ct][r] + bq[n];
                q = (q - mean[n]) * rsqrtf(var[n] + 1e-5f) * gamma[n] + beta[n];
                outB[(size_t)m * 512 + n] = f2bf(q);
            }
}

// ---------------------------------------------------------------------------
// megaQ2 (r19): ONE kernel = qproj (256 blocks, fp32-direct) + keys cvt
// (12800 blocks) + small cvt {x,sw1,sw3,sw2} + x row-sum (3840 blocks).
// qproj reads fp32 so nothing here depends on anything else -> full overlap.
// wq_b region is now dead (qproj converts inline).
// ---------------------------------------------------------------------------
__global__ __launch_bounds__(256) void megaQ2_kernel(
        const float* __restrict__ x, const float* __restrict__ wq,
        unsigned short* __restrict__ qb,
        const float* __restrict__ bq, const float* __restrict__ gamma,
        const float* __restrict__ beta, const float* __restrict__ mean,
        const float* __restrict__ var,
        const float* __restrict__ keys, unsigned short* __restrict__ keys_b,
        const float* __restrict__ sw1, const float* __restrict__ sw3,
        const float* __restrict__ sw2,
        unsigned short* __restrict__ x_b, unsigned short* __restrict__ sw1_b,
        unsigned short* __restrict__ sw3_b, unsigned short* __restrict__ sw2_b,
        float* __restrict__ sumx) {
    __shared__ alignas(16) char smem[18432];
    if (blockIdx.x < 256) {
        qproj_body(blockIdx.x, threadIdx.x, x, wq, qb, bq, gamma, beta,
                   mean, var, smem);
    } else if (blockIdx.x < 13056) {
        int i = (blockIdx.x - 256) * 256 + threadIdx.x;   // [0, 3276800)
        float4 f = ((const float4*)keys)[i];
        ushort4 o;
        o.x = f2bf(f.x); o.y = f2bf(f.y); o.z = f2bf(f.z); o.w = f2bf(f.w);
        ((ushort4*)keys_b)[i] = o;
    } else {
        int j = (blockIdx.x - 13056) * 256 + threadIdx.x; // [0, 983040)
        const float* src; unsigned short* dst; int base;
        if      (j < 393216) { src = x;   dst = x_b;   base = 0; }
        else if (j < 589824) { src = sw1; dst = sw1_b; base = 393216; }
        else if (j < 786432) { src = sw3; dst = sw3_b; base = 589824; }
        else                 { src = sw2; dst = sw2_b; base = 786432; }
        int k = j - base;
        float4 f = ((const float4*)src)[k];
        ushort4 o;
        o.x = f2bf(f.x); o.y = f2bf(f.y); o.z = f2bf(f.z); o.w = f2bf(f.w);
        ((ushort4*)dst)[k] = o;
        if (j < 393216) {                              // x region: fused row sum
            float s = f.x + f.y + f.z + f.w;
            #pragma unroll
            for (int off = 32; off > 0; off >>= 1) s += __shfl_down(s, off);
            if ((threadIdx.x & 63) == 0) atomicAdd(&sumx[j / 192], s);
        }
    }
}

// ---------------------------------------------------------------------------
// GEMM  C = A @ W^T  (64x64 tile, BK=64), +p0[m] epilogue -> fp32 (legacy).
// ---------------------------------------------------------------------------
__global__ __launch_bounds__(256) void gemm_nt2(
        const unsigned short* __restrict__ A, const unsigned short* __restrict__ W,
        int M, int N, int K, float* __restrict__ outF,
        const float* __restrict__ p0) {
    __shared__ alignas(16) short As[64][72];
    __shared__ alignas(16) short Ws[64][72];
    const int tid = threadIdx.x;
    const int m0 = blockIdx.x * 64, n0 = blockIdx.y * 64;
    const int wv = tid >> 6, lane = tid & 63;
    const int wr = wv >> 1, wc = wv & 1;
    const int lr = lane & 15, lq = lane >> 4;
    f32x4 acc[2][2];
    #pragma unroll
    for (int i = 0; i < 2; ++i)
        #pragma unroll
        for (int j = 0; j < 2; ++j) acc[i][j] = (f32x4){0.f, 0.f, 0.f, 0.f};
    for (int kb = 0; kb < K; kb += 64) {
        #pragma unroll
        for (int it = 0; it < 2; ++it) {
            int chunk = tid + it * 256;
            int row = chunk >> 3, c8 = (chunk & 7) * 8;
            *(s16x8*)&As[row][c8] = *(const s16x8*)(A + (size_t)(m0 + row) * K + kb + c8);
            *(s16x8*)&Ws[row][c8] = *(const s16x8*)(W + (size_t)(n0 + row) * K + kb + c8);
        }
        __syncthreads();
        #pragma unroll
        for (int ks = 0; ks < 2; ++ks) {
            const int k0 = ks * 32 + lq * 8;
            #pragma unroll
            for (int rt = 0; rt < 2; ++rt) {
                s16x8 a = *(const s16x8*)&As[wr * 32 + rt * 16 + lr][k0];
                #pragma unroll
                for (int ct = 0; ct < 2; ++ct) {
                    s16x8 b = *(const s16x8*)&Ws[wc * 32 + ct * 16 + lr][k0];
                    acc[rt][ct] = __builtin_amdgcn_mfma_f32_16x16x32_bf16(a, b, acc[rt][ct], 0, 0, 0);
                }
            }
        }
        __syncthreads();
    }
    #pragma unroll
    for (int rt = 0; rt < 2; ++rt)
        #pragma unroll
        for (int ct = 0; ct < 2; ++ct)
            #pragma unroll
            for (int r = 0; r < 4; ++r) {
                int m = m0 + wr * 32 + rt * 16 + lq * 4 + r;
                int n = n0 + wc * 32 + ct * 16 + lr;
                outF[(size_t)m * N + n] = acc[rt][ct][r] + p0[m];
            }
}

// ---------------------------------------------------------------------------
// SwiGLU-up body (h = silu(x@W1^T)*(x@W3^T) -> bf16, 2048x1024, K=768).
// ---------------------------------------------------------------------------
__device__ __forceinline__ void swiglu_body(
        int sb, int tid, const unsigned short* __restrict__ A,
        const unsigned short* __restrict__ W1, const unsigned short* __restrict__ W3,
        unsigned short* __restrict__ outB, char* smem) {
    short (*As)[72]  = (short(*)[72])smem;            //  9216 B
    short (*W1s)[72] = (short(*)[72])(smem + 9216);   //  9216 B
    short (*W3s)[72] = (short(*)[72])(smem + 18432);  //  9216 B
    const int m0 = (sb & 31) * 64, n0 = (sb >> 5) * 64;
    const int wv = tid >> 6, lane = tid & 63;
    const int wr = wv >> 1, wc = wv & 1;
    const int lr = lane & 15, lq = lane >> 4;
    f32x4 acc1[2][2], acc3[2][2];
    #pragma unroll
    for (int i = 0; i < 2; ++i)
        #pragma unroll
        for (int j = 0; j < 2; ++j) {
            acc1[i][j] = (f32x4){0.f, 0.f, 0.f, 0.f};
            acc3[i][j] = (f32x4){0.f, 0.f, 0.f, 0.f};
        }
    for (int kb = 0; kb < 768; kb += 64) {
        #pragma unroll
        for (int it = 0; it < 2; ++it) {
            int chunk = tid + it * 256;
            int row = chunk >> 3, c8 = (chunk & 7) * 8;
            *(s16x8*)&As[row][c8]  = *(const s16x8*)(A  + (size_t)(m0 + row) * 768 + kb + c8);
            *(s16x8*)&W1s[row][c8] = *(const s16x8*)(W1 + (size_t)(n0 + row) * 768 + kb + c8);
            *(s16x8*)&W3s[row][c8] = *(const s16x8*)(W3 + (size_t)(n0 + row) * 768 + kb + c8);
        }
        __syncthreads();
        #pragma unroll
        for (int ks = 0; ks < 2; ++ks) {
            const int k0 = ks * 32 + lq * 8;
            #pragma unroll
            for (int rt = 0; rt < 2; ++rt) {
                s16x8 a = *(const s16x8*)&As[wr * 32 + rt * 16 + lr][k0];
                #pragma unroll
                for (int ct = 0; ct < 2; ++ct) {
                    s16x8 b1 = *(const s16x8*)&W1s[wc * 32 + ct * 16 + lr][k0];
                    s16x8 b3 = *(const s16x8*)&W3s[wc * 32 + ct * 16 + lr][k0];
                    acc1[rt][ct] = __builtin_amdgcn_mfma_f32_16x16x32_bf16(a, b1, acc1[rt][ct], 0, 0, 0);
                    acc3[rt][ct] = __builtin_amdgcn_mfma_f32_16x16x32_bf16(a, b3, acc3[rt][ct], 0, 0, 0);
                }
            }
        }
        __syncthreads();
    }
    #pragma unroll
    for (int rt = 0; rt < 2; ++rt)
        #pragma unroll
        for (int ct = 0; ct < 2; ++ct)
            #pragma unroll
            for (int r = 0; r < 4; ++r) {
                int m = m0 + wr * 32 + rt * 16 + lq * 4 + r;
                int n = n0 + wc * 32 + ct * 16 + lr;
                float u1 = acc1[rt][ct][r], u3 = acc3[rt][ct][r];
                float hv = u1 / (1.f + expf(-u1)) * u3;
                outB[(size_t)m * 1024 + n] = f2bf(hv);
            }
}

// ---------------------------------------------------------------------------
// Down-proj body, RAW (out = h @ W2^T, 2048x768, K=1024).
// ---------------------------------------------------------------------------
__device__ __forceinline__ void down_body(
        int sb, int tid, const unsigned short* __restrict__ A,
        const unsigned short* __restrict__ W, float* __restrict__ outF,
        char* smem) {
    short (*As)[72] = (short(*)[72])smem;             //  9216 B
    short (*Ws)[72] = (short(*)[72])(smem + 9216);    //  9216 B
    const int m0 = (sb & 31) * 64, n0 = (sb >> 5) * 64;
    const int wv = tid >> 6, lane = tid & 63;
    const int wr = wv >> 1, wc = wv & 1;
    const int lr = lane & 15, lq = lane >> 4;
    f32x4 acc[2][2];
    #pragma unroll
    for (int i = 0; i < 2; ++i)
        #pragma unroll
        for (int j = 0; j < 2; ++j) acc[i][j] = (f32x4){0.f, 0.f, 0.f, 0.f};
    for (int kb = 0; kb < 1024; kb += 64) {
        #pragma unroll
        for (int it = 0; it < 2; ++it) {
            int chunk = tid + it * 256;
            int row = chunk >> 3, c8 = (chunk & 7) * 8;
            *(s16x8*)&As[row][c8] = *(const s16x8*)(A + (size_t)(m0 + row) * 1024 + kb + c8);
            *(s16x8*)&Ws[row][c8] = *(const s16x8*)(W + (size_t)(n0 + row) * 1024 + kb + c8);
        }
        __syncthreads();
        #pragma unroll
        for (int ks = 0; ks < 2; ++ks) {
            const int k0 = ks * 32 + lq * 8;
            #pragma unroll
            for (int rt = 0; rt < 2; ++rt) {
                s16x8 a = *(const s16x8*)&As[wr * 32 + rt * 16 + lr][k0];
                #pragma unroll
                for (int ct = 0; ct < 2; ++ct) {
                    s16x8 b = *(const s16x8*)&Ws[wc * 32 + ct * 16 + lr][k0];
                    acc[rt][ct] = __builtin_amdgcn_mfma_f32_16x16x32_bf16(a, b, acc[rt][ct], 0, 0, 0);
                }
            }
        }
        __syncthreads();
    }
    #pragma unroll
    for (int rt = 0; rt < 2; ++rt)
        #pragma unroll
        for (int ct = 0; ct < 2; ++ct)
            #pragma unroll
            for (int r = 0; r < 4; ++r) {
                int m = m0 + wr * 32 + rt * 16 + lq * 4 + r;
                int n = n0 + wc * 32 + ct * 16 + lr;
                outF[(size_t)m * 768 + n] = acc[rt][ct][r];
            }
}

// ---------------------------------------------------------------------------
// Score-pass body — r15 staged anchor (LOAD-BEARING; 5 restructurings all
// regressed: GRP=64 r9/r14, tt=2 r10/r12/r13, direct r16, pingpong r17).
// r19 additions, both OUTSIDE the staging/MFMA structure:
//  - maxbuf TRANSPOSED [128][8192] cell-major (r2-verified): coalesced pass-1
//    stores + coalesced theta loads.
//  - SKIP (subtile-skip): pass 1 wave-reduces each subtile's max over its
//    64 tokens x 16 experts -> submax[b][w][s] (bitwise = pass-2 scores).
//    Pass 2 skips a subtile's 16 MFMAs + LDS reads when submax < thmin
//    (wave-min theta): score <= submax < thmin <= theta[t] -> no survivor.
//    Exact; ~50% expected skip rate. Wave-uniform branch, prefetched loads.
// PASS 1: per-(lane,token) running max -> maxbuf (cell = (sp, lq)).
// PASS 2: recompute, compact (v,idx) >= theta[t,h] via atomicAdd, cap 64.
// ---------------------------------------------------------------------------
template <int PASS, int SKIP>
__device__ __forceinline__ void score_body(
        int b, int tid,
        const unsigned short* __restrict__ Q, const unsigned short* __restrict__ Kt,
        float* __restrict__ maxbuf, const float* __restrict__ theta,
        int* __restrict__ cnt, float2* __restrict__ buf,
        float* __restrict__ submax, char* smem) {
    short (*Ks)[GRP][136] = (short(*)[GRP][136])smem;   // [2][32][136]
    const int tile = b >> 7;                     // 128 = 4 heads x 32 splits
    const int hsp = b & 127;
    const int h = hsp >> 5, sp = hsp & 31;
    const int w = tid >> 6, lane = tid & 63;
    const int lr = lane & 15, lq = lane >> 4;
    const int t0 = tile * 256 + w * 64;
    const int nb0 = sp * SPN;

    s16x8 qf[4][4];
    #pragma unroll
    for (int tt = 0; tt < 4; ++tt) {
        const unsigned short* qp = Q + (size_t)(t0 + tt * 16 + lr) * 512 + h * 128 + lq * 8;
        #pragma unroll
        for (int ks = 0; ks < 4; ++ks) qf[tt][ks] = *(const s16x8*)(qp + ks * 32);
    }

    float runmax[4] = {NEG_INF, NEG_INF, NEG_INF, NEG_INF};
    float th[4];
    float thmin = NEG_INF;
    if (PASS == 2) {
        #pragma unroll
        for (int tt = 0; tt < 4; ++tt) th[tt] = theta[(t0 + tt * 16 + lr) * 4 + h];
        if (SKIP) {
            thmin = fminf(fminf(th[0], th[1]), fminf(th[2], th[3]));
            #pragma unroll
            for (int off = 32; off > 0; off >>= 1)
                thmin = fminf(thmin, __shfl_xor(thmin, off));
        }
    }
    const size_t sbase = ((size_t)b * 4 + w) * 50;
    float smc0 = 0.f, smc1 = 0.f;                // current group's subtile maxima
    if (PASS == 2 && SKIP) { smc0 = submax[sbase]; smc1 = submax[sbase + 1]; }

    const int srow = tid >> 4;                   // 0..15
    const int scol = (tid & 15) * 8;             // bf16 elem 0..120
    const unsigned short* kgp =
        Kt + ((size_t)h * 25600 + nb0 + srow) * 128 + scol;

    {   // prologue: stage group 0 into buffer 0
        *(s16x8*)&Ks[0][srow][scol]      = *(const s16x8*)kgp;
        *(s16x8*)&Ks[0][srow + 16][scol] = *(const s16x8*)(kgp + 2048);
    }

    for (int g = 0; g < NGRP; ++g) {
        s16x8 ka0, ka1;
        float smn0 = 0.f, smn1 = 0.f;
        if (g + 1 < NGRP) {
            const unsigned short* kp = kgp + (size_t)(g + 1) * 4096;
            ka0 = *(const s16x8*)kp;
            ka1 = *(const s16x8*)(kp + 2048);
            if (PASS == 2 && SKIP) {
                smn0 = submax[sbase + (g + 1) * 2];
                smn1 = submax[sbase + (g + 1) * 2 + 1];
            }
        }
        __syncthreads();
        const int cb = g & 1;
        #pragma unroll
        for (int st = 0; st < 2; ++st) {
            if (PASS == 2 && SKIP) {
                float sm = (st == 0) ? smc0 : smc1;
                if (sm < thmin) continue;        // wave-uniform exact skip
            }
            f32x4 acc[4];
            #pragma unroll
            for (int tt = 0; tt < 4; ++tt) acc[tt] = (f32x4){0.f, 0.f, 0.f, 0.f};
            #pragma unroll
            for (int ks = 0; ks < 4; ++ks) {
                s16x8 ka = *(const s16x8*)&Ks[cb][st * 16 + lr][ks * 32 + lq * 8];
                #pragma unroll
                for (int tt = 0; tt < 4; ++tt)
                    acc[tt] = __builtin_amdgcn_mfma_f32_16x16x32_bf16(ka, qf[tt][ks], acc[tt], 0, 0, 0);
            }
            if (PASS == 1) {
                float m0s[4];
                #pragma unroll
                for (int tt = 0; tt < 4; ++tt) {
                    m0s[tt] = fmaxf(fmaxf(acc[tt][0], acc[tt][1]),
                                    fmaxf(acc[tt][2], acc[tt][3]));
                    runmax[tt] = fmaxf(runmax[tt], m0s[tt]);
                }
                if (SKIP) {
                    float sm = fmaxf(fmaxf(m0s[0], m0s[1]), fmaxf(m0s[2], m0s[3]));
                    #pragma unroll
                    for (int off = 32; off > 0; off >>= 1)
                        sm = fmaxf(sm, __shfl_xor(sm, off));
                    if (lane == 0) submax[sbase + g * 2 + st] = sm;
                }
            } else {
                const int nb = nb0 + g * GRP + st * 16;
                #pragma unroll
                for (int tt = 0; tt < 4; ++tt) {
                    float m0 = fmaxf(fmaxf(acc[tt][0], acc[tt][1]),
                                     fmaxf(acc[tt][2], acc[tt][3]));
                    if (m0 >= th[tt]) {
                        int g4 = (t0 + tt * 16 + lr) * 4 + h;
                        #pragma unroll
                        for (int r = 0; r < 4; ++r) {
                            if (acc[tt][r] >= th[tt]) {
                                int n = nb + lq * 4 + r;   // D row = lq*4+r
                                int pos = atomicAdd(&cnt[g4], 1);
                                if (pos < 64) {
                                    float2 e; e.x = acc[tt][r]; e.y = __int_as_float(n);
                                    buf[(size_t)g4 * 64 + pos] = e;
                                }
                            }
                        }
                    }
                }
            }
        }
        if (g + 1 < NGRP) {
            const int nbuf = cb ^ 1;
            *(s16x8*)&Ks[nbuf][srow][scol]      = ka0;
            *(s16x8*)&Ks[nbuf][srow + 16][scol] = ka1;
            if (PASS == 2 && SKIP) { smc0 = smn0; smc1 = smn1; }
        }
    }

    if (PASS == 1) {
        #pragma unroll
        for (int tt = 0; tt < 4; ++tt)
            maxbuf[(size_t)(sp * 4 + lq) * 8192 + (t0 + tt * 16 + lr) * 4 + h] = runmax[tt];
    }
}

// ---------------------------------------------------------------------------
// Standalone score pass (legacy fallback, no skip).
// ---------------------------------------------------------------------------
template <int PASS>
__global__ __launch_bounds__(256, 4) void score_pass_kernel(
        const unsigned short* __restrict__ Q, const unsigned short* __restrict__ Kt,
        float* __restrict__ maxbuf, const float* __restrict__ theta,
        int* __restrict__ cnt, float2* __restrict__ buf) {
    __shared__ alignas(16) char smem[17408];
    score_body<PASS, 0>(blockIdx.x, threadIdx.x, Q, Kt, maxbuf, theta, cnt, buf,
                        nullptr, smem);
}

// ---------------------------------------------------------------------------
// Fused mega-kernels: dense-GEMM blocks FIRST, score blocks after.
// Offsets 512/384 are =0 mod 8 -> score slab->XCD co-location preserved.
// ---------------------------------------------------------------------------
__global__ __launch_bounds__(256, 4) void megaA_kernel(   // swiglu(512) + score1(1024)
        const unsigned short* __restrict__ xb, const unsigned short* __restrict__ w1,
        const unsigned short* __restrict__ w3, unsigned short* __restrict__ hb,
        const unsigned short* __restrict__ Q, const unsigned short* __restrict__ Kt,
        float* __restrict__ maxbuf, float* __restrict__ submax) {
    __shared__ alignas(16) char smem[27648];
    if (blockIdx.x < 512)
        swiglu_body(blockIdx.x, threadIdx.x, xb, w1, w3, hb, smem);
    else
        score_body<1, 1>(blockIdx.x - 512, threadIdx.x, Q, Kt, maxbuf,
                         nullptr, nullptr, nullptr, submax, smem);
}

__global__ __launch_bounds__(256, 4) void megaB_kernel(   // down(384) + score2(1024)
        const unsigned short* __restrict__ hb, const unsigned short* __restrict__ w2,
        float* __restrict__ outF,
        const unsigned short* __restrict__ Q, const unsigned short* __restrict__ Kt,
        const float* __restrict__ theta, int* __restrict__ cnt,
        float2* __restrict__ buf, float* __restrict__ submax) {
    __shared__ alignas(16) char smem[18432];
    if (blockIdx.x < 384)
        down_body(blockIdx.x, threadIdx.x, hb, w2, outF, smem);
    else
        score_body<2, 1>(blockIdx.x - 384, threadIdx.x, Q, Kt, nullptr,
                         theta, cnt, buf, submax, smem);
}

// ---------------------------------------------------------------------------
// theta = 16th-largest of the 128 cell maxima per (t,h). maxbuf is
// cell-major [128][8192] (r2-verified) -> loads here are coalesced.
// ---------------------------------------------------------------------------
__global__ __launch_bounds__(64) void theta_kernel(
        const float* __restrict__ maxbuf, float* __restrict__ theta) {
    int g = blockIdx.x * 64 + threadIdx.x;
    if (g >= 8192) return;
    const float* mb = maxbuf + g;
    float s[16];
    #pragma unroll
    for (int i = 0; i < 16; ++i) s[i] = NEG_INF;
    for (int j = 0; j < 128; ++j) {
        float v = mb[(size_t)j * 8192];
        if (v > s[15]) {
            #pragma unroll
            for (int i = 15; i > 0; --i)
                s[i] = (v > s[i - 1]) ? s[i - 1] : ((v > s[i]) ? v : s[i]);
            s[0] = (v > s[0]) ? v : s[0];
        }
    }
    theta[g] = s[15];
}

// ---------------------------------------------------------------------------
// Finalize. Block = token t (4 waves = 4 heads). Exact top-16 via rank,
// softmax, tiny MLP (reassociated). FUSE_OUT=1: block-reduce 4 head contribs
// and add to out[t][:] (out holds raw down-proj). FUSE_OUT=0: legacy.
// ---------------------------------------------------------------------------
template <int FUSE_OUT>
__global__ __launch_bounds__(256) void finalize_kernel(
        const int* __restrict__ cnt, const float2* __restrict__ buf,
        const float* __restrict__ sumx,
        const float* __restrict__ wdown, const float* __restrict__ wup,
        const float* __restrict__ aw1, const float* __restrict__ aw2,
        const float* __restrict__ aw3, float* __restrict__ combsum,
        float* __restrict__ out) {
    __shared__ float zsh[4][16];
    __shared__ float wsh[4][16];
    __shared__ float csh[4];
    const int wv = threadIdx.x >> 6, lane = threadIdx.x & 63;
    const int t = blockIdx.x;
    const int g = t * 4 + wv;
    int c = cnt[g]; c = (c > 64) ? 64 : c;       // >=16 guaranteed by theta

    float v = NEG_INF; int n = 0x7fffffff;
    if (lane < c) {
        float2 e = buf[(size_t)g * 64 + lane];
        v = e.x; n = __float_as_int(e.y);
    }
    int r = 0;
    for (int i = 0; i < c; ++i) {
        float vi = __shfl(v, i);
        int   ni = __shfl(n, i);
        r += ((vi > v) || (vi == v && ni < n)) ? 1 : 0;
    }
    float m = v;
    #pragma unroll
    for (int off = 32; off > 0; off >>= 1) m = fmaxf(m, __shfl_xor(m, off));
    const bool sel = (lane < c) && (r < 16);
    float e = sel ? expf(v - m) : 0.f;
    float den = e;
    #pragma unroll
    for (int off = 32; off > 0; off >>= 1) den += __shfl_xor(den, off);
    if (sel) {
        zsh[wv][r] = sumx[t] * wdown[n];
        wsh[wv][r] = (e / den) * wup[n];
    }
    __syncthreads();
    float contrib = 0.f;
    if (lane < 44) {
        float u1 = 0.f, u3 = 0.f, cj = 0.f;
        #pragma unroll
        for (int k = 0; k < 16; ++k) {
            float zk = zsh[wv][k];
            u1 += zk * aw1[lane * 16 + k];
            u3 += zk * aw3[lane * 16 + k];
            cj += wsh[wv][k] * aw2[k * 44 + lane];
        }
        float gj = u1 / (1.f + expf(-u1)) * u3;
        contrib = gj * cj;
    }
    #pragma unroll
    for (int off = 32; off > 0; off >>= 1) contrib += __shfl_xor(contrib, off);
    if (FUSE_OUT) {
        if (lane == 0) csh[wv] = contrib;
        __syncthreads();
        float comb = csh[0] + csh[1] + csh[2] + csh[3];
        float* orow = out + (size_t)t * 768;
        #pragma unroll
        for (int i = 0; i < 3; ++i) orow[threadIdx.x + i * 256] += comb;
    } else {
        if (lane == 0) atomicAdd(&combsum[t], contrib);
    }
}

// ---------------------------------------------------------------------------
// Legacy standalone SwiGLU (fallback path).
// ---------------------------------------------------------------------------
__global__ __launch_bounds__(256) void gemm_swiglu_kernel(
        const unsigned short* __restrict__ A, const unsigned short* __restrict__ W1,
        const unsigned short* __restrict__ W3, unsigned short* __restrict__ outB) {
    __shared__ alignas(16) char smem[27648];
    swiglu_body(blockIdx.x, threadIdx.x, A, W1, W3, outB, smem);
}

// ---------------------------------------------------------------------------
// Host launch
// ---------------------------------------------------------------------------
extern "C" void kernel_launch(void* const* d_in, const int* in_sizes, int n_in,
                              void* d_out, int out_size, void* d_ws, size_t ws_size,
                              hipStream_t stream) {
    const float* x     = (const float*)d_in[0];
    const float* wq    = (const float*)d_in[1];
    const float* bq    = (const float*)d_in[2];
    const float* gamma = (const float*)d_in[3];
    const float* beta  = (const float*)d_in[4];
    const float* mean  = (const float*)d_in[5];
    const float* var   = (const float*)d_in[6];
    const float* keys  = (const float*)d_in[7];
    const float* wdown = (const float*)d_in[8];
    const float* wup   = (const float*)d_in[9];
    const float* aw1   = (const float*)d_in[10];
    const float* aw2   = (const float*)d_in[11];
    const float* aw3   = (const float*)d_in[12];
    const float* sw1   = (const float*)d_in[13];
    const float* sw2   = (const float*)d_in[14];
    const float* sw3   = (const float*)d_in[15];
    float* out = (float*)d_out;

    char* ws = (char*)d_ws;
    unsigned short* x_b    = (unsigned short*)(ws + 0);         // 3,145,728 B
    // ws+3,145,728: dead region (wq_b no longer materialized)
    unsigned short* sw1_b  = (unsigned short*)(ws + 3932160);   // 1,572,864
    unsigned short* sw3_b  = (unsigned short*)(ws + 5505024);   // 1,572,864
    unsigned short* sw2_b  = (unsigned short*)(ws + 7077888);   // 1,572,864
    unsigned short* keys_b = (unsigned short*)(ws + 8650752);   // 26,214,400
    unsigned short* q_b    = (unsigned short*)(ws + 34865152);  // 2,097,152
    float* sumx    = (float*)(ws + 36962304);                   //     8,192 }
    float* theta   = (float*)(ws + 36970496);                   //    32,768 } one
    float* combsum = (float*)(ws + 37003264);                   //     8,192 } memset
    int*   cnt     = (int*)  (ws + 37011456);                   //    32,768 }
    // R1 (4 MB): maxbuf (A-phase) -> buf (B-phase).
    char* R1 = ws + 37044224;
    float* maxbuf = (float*)R1;
    float2* buf   = (float2*)R1;
    unsigned short* h_b_fused = (unsigned short*)(ws + 41238528);  // 4 MB
    float* submax = (float*)(ws + 45432832);                    //   819,200
    const bool fused = ws_size >= 46252032ull;                  // end of submax

    // memset FIRST (sumx accumulated by megaQ2's fused row-sum)
    hipMemsetAsync(ws + 36962304, 0, 81920, stream);
    // qproj (fp32-direct) + keys cvt + small cvt + row-sum, one kernel
    megaQ2_kernel<<<16896, 256, 0, stream>>>(x, wq, q_b, bq, gamma, beta,
                                             mean, var, keys, keys_b,
                                             sw1, sw3, sw2,
                                             x_b, sw1_b, sw3_b, sw2_b, sumx);
    if (fused) {
        // A: swiglu (512) + score pass 1 (1024, writes maxbuf + submax)
        megaA_kernel<<<1536, 256, 0, stream>>>(x_b, sw1_b, sw3_b, h_b_fused,
                                               q_b, keys_b, maxbuf, submax);
        theta_kernel<<<128, 64, 0, stream>>>(maxbuf, theta);
        // B: down-proj raw -> out (384) + score pass 2 (1024, subtile-skip)
        megaB_kernel<<<1408, 256, 0, stream>>>(h_b_fused, sw2_b, out,
                                               q_b, keys_b, theta, cnt, buf, submax);
        // top-16 + gates + tiny MLP; adds comb to out rows directly
        finalize_kernel<1><<<2048, 256, 0, stream>>>(cnt, buf, sumx, wdown, wup,
                                                     aw1, aw2, aw3, combsum, out);
    } else {
        // legacy sequence (no skip; h_b reuses R1 after finalize)
        unsigned short* h_b = (unsigned short*)R1;
        score_pass_kernel<1><<<1024, 256, 0, stream>>>(q_b, keys_b, maxbuf, nullptr, nullptr, nullptr);
        theta_kernel<<<128, 64, 0, stream>>>(maxbuf, theta);
        score_pass_kernel<2><<<1024, 256, 0, stream>>>(q_b, keys_b, nullptr, theta, cnt, buf);
        finalize_kernel<0><<<2048, 256, 0, stream>>>(cnt, buf, sumx, wdown, wup,
                                                     aw1, aw2, aw3, combsum, nullptr);
        gemm_swiglu_kernel<<<512, 256, 0, stream>>>(x_b, sw1_b, sw3_b, h_b);
        gemm_nt2<<<dim3(32, 12), 256, 0, stream>>>(h_b, sw2_b, 2048, 768, 1024,
                                                   out, combsum);
    }
}